// Round 16
// baseline (175.208 us; speedup 1.0000x reference)
//
#include <hip/hip_runtime.h>
#include <math.h>

typedef __attribute__((ext_vector_type(8))) _Float16 f16x8;
typedef __attribute__((ext_vector_type(4))) float    f32x4;

static constexpr int cB  = 8;
static constexpr int cN  = 4096;
static constexpr int cD  = 256;
static constexpr int cBN = cB * cN;
#define PI_F 3.14159265358979323846f

__device__ __forceinline__ float2 cmul(float2 a, float2 b) {
    return make_float2(a.x*b.x - a.y*b.y, a.x*b.y + a.y*b.x);
}
__device__ __forceinline__ float2 cfma2(float2 a, float2 b, float2 acc) {
    acc.x += a.x*b.x - a.y*b.y;
    acc.y += a.x*b.y + a.y*b.x;
    return acc;
}
__device__ __forceinline__ float2 cneg(float2 a) { return make_float2(-a.x, -a.y); }

struct G4 { float2 ii, ij, ji, jj; };

__device__ __forceinline__ G4 givens_f(float al, float be, float ga) {
    float ra = (al + be) * (PI_F * 0.5f);
    float rs = (al - be) * (PI_F * 0.5f);
    float gm = ga * (PI_F * 0.5f);
    float sg, cg, sra, cra, srs, crs;
    sincosf(gm, &sg, &cg);
    sincosf(ra, &sra, &cra);
    sincosf(rs, &srs, &crs);
    G4 g;
    g.ii = make_float2( cra*cg, -sra*cg);
    g.ij = make_float2( crs*sg, -srs*sg);
    g.ji = make_float2(-crs*sg, -srs*sg);
    g.jj = make_float2( cra*cg,  sra*cg);
    return g;
}

__global__ void sentinel_kernel(float* out, int n, float v) {
    if (n > 0) out[0] = v;
    if (n > 1) out[1] = v;
}

// ---------------------------------------------------------------------------
// Weight convert: fp32 W -> f16. Layout: W16[m][65536], m={ev1,ev2,hp1,hp2}.
// ---------------------------------------------------------------------------
__global__ __launch_bounds__(256) void wcvt_kernel(
    const float* __restrict__ w0, const float* __restrict__ w1,
    const float* __restrict__ w2, const float* __restrict__ w3,
    _Float16* __restrict__ W16)
{
    int i = blockIdx.x * 256 + threadIdx.x;   // 0..65535
    const float* src[4] = {w0, w1, w2, w3};
    #pragma unroll
    for (int m = 0; m < 4; ++m)
        W16[(size_t)m*65536 + i] = (_Float16)src[m][i];
}

// ---------------------------------------------------------------------------
// SIREN v2: row-ownership. Block = 128 rows x 256 cols, 8 waves; wave w owns
// rows [w*16, w*16+16) x ALL 256 cols (acc = 16 f32x4). All reductions
// (ScaleNorm / eig / pool) are wave-local; after the x-stage barrier there
// are NO __syncthreads — wave-local LDS RAW ordered by lgkmcnt(0) (in-order
// DS pipe per wave) + sched_barrier. launch_bounds(512,2): 128-VGPR cap.
// ---------------------------------------------------------------------------
__device__ __forceinline__ void wave_wait_lds() {
    asm volatile("s_waitcnt lgkmcnt(0)" ::: "memory");
    __builtin_amdgcn_sched_barrier(0);
}

__device__ __forceinline__ f16x8 ld_a(const _Float16* buf, int row, int k0, int kq)
{
    int off = ((k0*2 + kq*16) ^ ((row & 7) << 4));
    return *(const f16x8*)((const char*)buf + row*512 + off);
}

__device__ __forceinline__ f16x8 ld_w(const _Float16* __restrict__ wP,
                                      int nt, int kk, int lr, int kq)
{
    return *(const f16x8*)(wP + (nt*16 + lr)*256 + kk*32 + kq*8);
}

__device__ __forceinline__ void gemmR(const _Float16* buf,
                                      const _Float16* __restrict__ wP,
                                      int wrow, int lr, int kq, f32x4 acc[16])
{
    #pragma unroll
    for (int kk = 0; kk < 8; ++kk) {
        f16x8 ah = ld_a(buf, wrow + lr, kk*32, kq);
        f16x8 b0 = ld_w(wP, 0, kk, lr, kq);
        f16x8 b1;
        #pragma unroll
        for (int nt = 0; nt < 16; ++nt) {
            if ((nt & 1) == 0) {
                if (nt < 15) b1 = ld_w(wP, nt+1, kk, lr, kq);
                acc[nt] = __builtin_amdgcn_mfma_f32_16x16x32_f16(ah, b0, acc[nt], 0, 0, 0);
            } else {
                if (nt < 15) b0 = ld_w(wP, nt+1, kk, lr, kq);
                acc[nt] = __builtin_amdgcn_mfma_f32_16x16x32_f16(ah, b1, acc[nt], 0, 0, 0);
            }
        }
    }
}

__global__ __launch_bounds__(512, 2) void siren_mfma(
    const float* __restrict__ x, const _Float16* __restrict__ W16,
    const float* __restrict__ ev_b1, const float* __restrict__ ev_g,
    const float* __restrict__ ev_b2,
    const float* __restrict__ hp_b1, const float* __restrict__ hp_g,
    const float* __restrict__ hp_b2,
    const float* __restrict__ cheb,
    float* __restrict__ Pout, float2* __restrict__ DIAG)
{
    __shared__ _Float16 buf[128*256];   // 64 KB

    const int tid  = threadIdx.x;
    const int w    = tid >> 6;          // 0..7
    const int lane = tid & 63;
    const int lr   = lane & 15;
    const int kq   = lane >> 4;
    const int wrow = w * 16;            // wave's first block-local row
    const size_t r0 = (size_t)blockIdx.x * 128;
    const int b   = (int)(r0 >> 12);
    const int net = blockIdx.y;         // 0 = EV, 1 = HP

    const _Float16* w1P = W16 + (size_t)(net*2 + 0)*65536;
    const _Float16* w2P = W16 + (size_t)(net*2 + 1)*65536;
    const float* b1 = net ? hp_b1 : ev_b1;
    const float* b2 = net ? hp_b2 : ev_b2;
    const float  g  = net ? hp_g[0] : ev_g[0];

    {   // stage x: 128 rows x 256 cols -> f16 swizzled
        const int row = tid >> 2;
        const int c0  = (tid & 3) * 64;
        const float4* src = (const float4*)(x + (r0 + row)*256 + c0);
        const int swz = (row & 7) << 4;
        #pragma unroll
        for (int j = 0; j < 8; ++j) {
            float4 p = src[2*j], q = src[2*j+1];
            f16x8 h;
            h[0]=(_Float16)p.x; h[1]=(_Float16)p.y; h[2]=(_Float16)p.z; h[3]=(_Float16)p.w;
            h[4]=(_Float16)q.x; h[5]=(_Float16)q.y; h[6]=(_Float16)q.z; h[7]=(_Float16)q.w;
            int off = (((c0 + j*8) * 2) ^ swz);
            *(f16x8*)((char*)buf + row*512 + off) = h;
        }
    }
    __syncthreads();   // the ONLY block-wide barrier

    f32x4 acc[16];
    #pragma unroll
    for (int nt = 0; nt < 16; ++nt) acc[nt] = (f32x4)(0.f);
    gemmR(buf, w1P, wrow, lr, kq, acc);

    {   // L1 epilogue (wave-local): sin + ScaleNorm -> act overwrites own rows
        float rs[4] = {0.f, 0.f, 0.f, 0.f};
        #pragma unroll
        for (int nt = 0; nt < 16; ++nt) {
            float bv = b1[nt*16 + lr];
            #pragma unroll
            for (int r = 0; r < 4; ++r) {
                float v = __sinf(acc[nt][r] + bv);
                rs[r] += v*v;
            }
        }
        #pragma unroll
        for (int mk = 1; mk < 16; mk <<= 1)
            #pragma unroll
            for (int r = 0; r < 4; ++r) rs[r] += __shfl_xor(rs[r], mk);
        float sc[4];
        #pragma unroll
        for (int r = 0; r < 4; ++r) sc[r] = g / fmaxf(sqrtf(rs[r]), 1e-5f);
        #pragma unroll
        for (int nt = 0; nt < 16; ++nt) {
            float bv = b1[nt*16 + lr];
            #pragma unroll
            for (int r = 0; r < 4; ++r) {
                float v = __sinf(acc[nt][r] + bv) * sc[r];
                int row = wrow + kq*4 + r;
                int col = nt*16 + lr;
                *(_Float16*)((char*)buf + row*512 + ((col*2) ^ ((row & 7) << 4))) = (_Float16)v;
            }
        }
    }
    wave_wait_lds();   // intra-wave RAW: act writes -> gemm2 reads (same rows)

    #pragma unroll
    for (int nt = 0; nt < 16; ++nt) acc[nt] = (f32x4)(0.f);
    gemmR(buf, w2P, wrow, lr, kq, acc);

    if (net == 0) {   // eig -> DIAG (wave-local)
        float es[4] = {0.f, 0.f, 0.f, 0.f};
        #pragma unroll
        for (int nt = 0; nt < 16; ++nt) {
            float bv = b2[nt*16 + lr];
            #pragma unroll
            for (int r = 0; r < 4; ++r) es[r] += __sinf(acc[nt][r] + bv);
        }
        #pragma unroll
        for (int mk = 1; mk < 16; mk <<= 1)
            #pragma unroll
            for (int r = 0; r < 4; ++r) es[r] += __shfl_xor(es[r], mk);
        // uniform precompute (avoid divergent doubles)
        float dmp[9];
        {
            const double c = 3.14159265358979323846 / 10.0;
            double sc_ = sin(c), cc = cos(c);
            dmp[0] = 1.f;
            #pragma unroll
            for (int k = 1; k < 9; ++k)
                dmp[k] = (float)(((10.0 - k) * sc_ * cos(k*c) + cc * sin(k*c)) / (10.0 * sc_));
        }
        const float* cf = cheb + b*9;
        #pragma unroll
        for (int r = 0; r < 4; ++r) {
            if (lr == r) {
                float ev = es[r] * (1.f/256.f);
                float t0 = 1.f, t1 = ev;
                float filt = cf[0] + ev * cf[1] * dmp[1];
                #pragma unroll
                for (int k = 2; k < 9; ++k) {
                    float t2 = 2.f*ev*t1 - t0;
                    filt += t2 * cf[k] * dmp[k];
                    t0 = t1; t1 = t2;
                }
                float sp, cp;
                sincosf(PI_F * ev, &sp, &cp);
                DIAG[r0 + wrow + kq*4 + r] = make_float2(filt*cp, filt*sp);
            }
        }
    } else {          // pool -> Pout (wave-local)
        #pragma unroll
        for (int nt = 0; nt < 16; ++nt) {
            float bv = b2[nt*16 + lr];
            #pragma unroll
            for (int r = 0; r < 4; ++r) {
                float v = __sinf(acc[nt][r] + bv);
                int row = wrow + kq*4 + r;
                int col = nt*16 + lr;
                *(_Float16*)((char*)buf + row*512 + ((col*2) ^ ((row & 7) << 4))) = (_Float16)v;
            }
        }
        wave_wait_lds();   // intra-wave: sine writes -> pool reads (same rows)
        const int sb[6] = {0, 42, 85, 128, 170, 213};
        const int eb[6] = {43, 86, 128, 171, 214, 256};
        const float inv[6] = {1.f/43.f, 1.f/44.f, 1.f/43.f, 1.f/43.f, 1.f/44.f, 1.f/43.f};
        for (int t = lane; t < 96; t += 64) {   // 16 rows x 6 bins per wave
            int rr = t / 6, q = t - rr*6;
            int row = wrow + rr;
            int swz = (row & 7) << 4;
            float s = 0.f;
            for (int c = sb[q]; c < eb[q]; ++c)
                s += (float)(*(const _Float16*)((const char*)buf + row*512 + ((c*2) ^ swz)));
            int nn = (int)(r0 & 4095) + row;
            Pout[(size_t)b*6*cN + nn*6 + q] = s * inv[q];
        }
    }
}

// ---------------------------------------------------------------------------
// DHHP: 9-band operator T = L' U' D L U composed in-block (32 lanes), then
// float4 9-tap stencil over a 32-row x 256-col tile.
// ---------------------------------------------------------------------------
__global__ __launch_bounds__(256) void dhhp_stencil(
    const float* __restrict__ x, const float* __restrict__ P,
    const float2* __restrict__ DIAG, float* __restrict__ outf,
    unsigned long long out_floats, int mode)
{
    __shared__ float  xsr[40*256];
    __shared__ G4 uG[41], lG[41];
    __shared__ float2 cDg[40];
    __shared__ float2 cT[32][9];

    const int tid = threadIdx.x;
    const int n0 = blockIdx.x * 32;
    const int b  = blockIdx.y;
    const size_t bbase = (size_t)b * cN;
    const int b6 = b * 6 * cN;
    const float2 z2 = make_float2(0.f, 0.f);
    const int jb = n0 - 5;

    for (int idx = tid; idx < 40*64; idx += 256) {   // float4 staging
        int r = idx >> 6, d4 = idx & 63;
        int m = n0 - 4 + r;
        float4 v = make_float4(0.f, 0.f, 0.f, 0.f);
        if (m >= 0 && m < cN) v = *(const float4*)(x + (bbase + m)*cD + d4*4);
        *(float4*)(xsr + r*256 + d4*4) = v;
    }
    if (tid < 82) {
        int t = (tid < 41) ? tid : tid - 41;
        int j = jb + t;
        G4 g; g.ii = g.ij = g.ji = g.jj = z2;
        if (j >= 0 && j <= cN-2) {
            if (tid < 41) g = givens_f(P[b6+3*cN+j], P[b6+4*cN+j], P[b6+5*cN+j]);   // u[j]
            else          g = givens_f(P[b6+j+1],    P[b6+cN+j+1], P[b6+2*cN+j+1]); // l[j]
        }
        if (tid < 41) uG[t] = g; else lG[t] = g;
    } else if (tid < 122) {
        int t = tid - 82;
        int m = n0 - 4 + t;
        cDg[t] = (m >= 0 && m < cN) ? DIAG[bbase + m] : z2;
    }
    __syncthreads();

    if (tid < 32) {
        const int m = n0 + tid;
        auto scoef = [&](int s, int rr, float2& A, float2& B, float2& C) {
            A = z2; B = z2; C = z2;
            if (rr < 0 || rr >= cN) return;
            if (s == 1) {
                if (rr == 0)         { G4 u0 = uG[0-jb]; B = u0.ii; C = u0.ij; }
                else if (rr == cN-1) { G4 up = uG[rr-1-jb]; A = up.ji; B = up.jj; }
                else { G4 up = uG[rr-1-jb], uc = uG[rr-jb];
                       A = up.ji; B = cmul(up.jj, uc.ii); C = cmul(up.jj, uc.ij); }
            } else if (s == 2) {
                if (rr == 0)         { G4 l0 = lG[0-jb]; B = l0.ii; C = l0.ij; }
                else if (rr == cN-1) { G4 lp = lG[rr-1-jb]; A = lp.ji; B = lp.jj; }
                else { G4 lp = lG[rr-1-jb], lc = lG[rr-jb];
                       A = cmul(lc.ii, lp.ji); B = cmul(lc.ii, lp.jj); C = lc.ij; }
            } else if (s == 3) {
                if (rr == 0)         { G4 u0 = uG[0-jb]; B = u0.jj; C = cneg(u0.ij); }
                else if (rr == cN-1) { G4 up = uG[rr-1-jb]; A = cneg(up.ji); B = up.ii; }
                else { G4 up = uG[rr-1-jb], uc = uG[rr-jb];
                       A = cneg(up.ji); B = cmul(up.ii, uc.jj); C = cneg(cmul(up.ii, uc.ij)); }
            } else {
                if (rr == 0)         { G4 l0 = lG[0-jb]; B = l0.jj; C = cneg(l0.ij); }
                else if (rr == cN-1) { G4 lp = lG[rr-1-jb]; A = cneg(lp.ji); B = lp.ii; }
                else { G4 lp = lG[rr-1-jb], lc = lG[rr-jb];
                       A = cneg(cmul(lc.jj, lp.ji)); B = cmul(lc.jj, lp.ii); C = cneg(lc.ij); }
            }
        };

        float2 wv[9], nw[9];
        #pragma unroll
        for (int k = 0; k < 9; ++k) wv[k] = z2;
        {
            float2 A, B, C; scoef(4, m, A, B, C);
            wv[3] = A; wv[4] = B; wv[5] = C;
        }
        #pragma unroll
        for (int k = 0; k < 9; ++k) nw[k] = z2;
        #pragma unroll
        for (int i = 3; i <= 5; ++i) {
            float2 A, B, C; scoef(3, m + i - 4, A, B, C);
            nw[i-1] = cfma2(wv[i], A, nw[i-1]);
            nw[i]   = cfma2(wv[i], B, nw[i]);
            nw[i+1] = cfma2(wv[i], C, nw[i+1]);
        }
        #pragma unroll
        for (int k = 0; k < 9; ++k) wv[k] = nw[k];
        #pragma unroll
        for (int k = 2; k <= 6; ++k) wv[k] = cmul(wv[k], cDg[tid + k]);
        #pragma unroll
        for (int k = 0; k < 9; ++k) nw[k] = z2;
        #pragma unroll
        for (int i = 2; i <= 6; ++i) {
            float2 A, B, C; scoef(2, m + i - 4, A, B, C);
            nw[i-1] = cfma2(wv[i], A, nw[i-1]);
            nw[i]   = cfma2(wv[i], B, nw[i]);
            nw[i+1] = cfma2(wv[i], C, nw[i+1]);
        }
        #pragma unroll
        for (int k = 0; k < 9; ++k) wv[k] = nw[k];
        #pragma unroll
        for (int k = 0; k < 9; ++k) nw[k] = z2;
        #pragma unroll
        for (int i = 1; i <= 7; ++i) {
            float2 A, B, C; scoef(1, m + i - 4, A, B, C);
            nw[i-1] = cfma2(wv[i], A, nw[i-1]);
            nw[i]   = cfma2(wv[i], B, nw[i]);
            nw[i+1] = cfma2(wv[i], C, nw[i+1]);
        }
        #pragma unroll
        for (int k = 0; k < 9; ++k) cT[tid][k] = nw[k];
    }
    __syncthreads();

    for (int idx = tid; idx < 32*64; idx += 256) {   // 8 float4 outputs/thread
        int r = idx >> 6, d4 = idx & 63;
        float4 ox = make_float4(0.f, 0.f, 0.f, 0.f);
        float4 oy = make_float4(0.f, 0.f, 0.f, 0.f);
        #pragma unroll
        for (int j = 0; j < 9; ++j) {
            float4 xv = *(const float4*)(xsr + (r + j)*256 + d4*4);
            float2 t = cT[r][j];
            ox.x = fmaf(t.x, xv.x, ox.x); ox.y = fmaf(t.x, xv.y, ox.y);
            ox.z = fmaf(t.x, xv.z, ox.z); ox.w = fmaf(t.x, xv.w, ox.w);
            oy.x = fmaf(t.y, xv.x, oy.x); oy.y = fmaf(t.y, xv.y, oy.y);
            oy.z = fmaf(t.y, xv.z, oy.z); oy.w = fmaf(t.y, xv.w, oy.w);
        }
        unsigned long long ci = (unsigned long long)((bbase + n0 + r)*(size_t)cD + d4*4);
        if (mode == 0) {
            if (ci + 4ULL <= out_floats) *(float4*)(outf + ci) = ox;
        } else {
            if (2ULL*(ci + 4ULL) <= out_floats) {
                float2* o2 = (float2*)outf + ci;
                o2[0] = make_float2(ox.x, oy.x);
                o2[1] = make_float2(ox.y, oy.y);
                o2[2] = make_float2(ox.z, oy.z);
                o2[3] = make_float2(ox.w, oy.w);
            }
        }
    }
}

// ---------------------------------------------------------------------------
extern "C" void kernel_launch(void* const* d_in, const int* in_sizes, int n_in,
                              void* d_out, int out_size, void* d_ws, size_t ws_size,
                              hipStream_t stream)
{
    const int expect[12] = { cBN*cD, cD*cD, cD, 1, cD*cD, cD,
                             cD*cD, cD, 1, cD*cD, cD, cB*9 };
    bool ok = (n_in == 12);
    if (ok) for (int i = 0; i < 12; ++i) ok = ok && (in_sizes[i] == expect[i]);
    if (!ok) {
        sentinel_kernel<<<1, 1, 0, stream>>>((float*)d_out, out_size, 1.0e6f);
        return;
    }
    const size_t pBytes = (size_t)cB * 6 * cN * sizeof(float);       // 768 KB
    const size_t dBytes = (size_t)cBN * sizeof(float2);              // 256 KB
    const size_t wBytes = (size_t)4 * 65536 * sizeof(_Float16);      // 512 KB
    if (d_ws == nullptr || ws_size < pBytes + dBytes + wBytes) {
        sentinel_kernel<<<1, 1, 0, stream>>>((float*)d_out, out_size, 2.0e6f);
        return;
    }
    int mode;
    if (out_size == cBN * cD)          mode = 0;
    else if (out_size == 2 * cBN * cD) mode = 1;
    else {
        sentinel_kernel<<<1, 1, 0, stream>>>((float*)d_out, out_size, 3.0e6f);
        return;
    }

    const float* x     = (const float*)d_in[0];
    const float* ev_w1 = (const float*)d_in[1];
    const float* ev_b1 = (const float*)d_in[2];
    const float* ev_g  = (const float*)d_in[3];
    const float* ev_w2 = (const float*)d_in[4];
    const float* ev_b2 = (const float*)d_in[5];
    const float* hp_w1 = (const float*)d_in[6];
    const float* hp_b1 = (const float*)d_in[7];
    const float* hp_g  = (const float*)d_in[8];
    const float* hp_w2 = (const float*)d_in[9];
    const float* hp_b2 = (const float*)d_in[10];
    const float* cheb  = (const float*)d_in[11];

    float*     P    = (float*)d_ws;
    float2*    DIAG = (float2*)((char*)d_ws + pBytes);
    _Float16*  W16  = (_Float16*)((char*)d_ws + pBytes + dBytes);

    wcvt_kernel<<<dim3(256), 256, 0, stream>>>(ev_w1, ev_w2, hp_w1, hp_w2, W16);
    siren_mfma<<<dim3(cBN/128, 2), 512, 0, stream>>>(x, W16, ev_b1, ev_g, ev_b2,
                                                     hp_b1, hp_g, hp_b2, cheb, P, DIAG);
    dhhp_stencil<<<dim3(cN/32, cB), 256, 0, stream>>>(x, P, DIAG, (float*)d_out,
                                                      (unsigned long long)out_size,
                                                      mode);
}

// Round 17
// 105.066 us; speedup vs baseline: 1.6676x; 1.6676x over previous
//
#include <hip/hip_runtime.h>
#include <math.h>

typedef __attribute__((ext_vector_type(8))) _Float16 f16x8;
typedef __attribute__((ext_vector_type(4))) float    f32x4;

static constexpr int cB  = 8;
static constexpr int cN  = 4096;
static constexpr int cD  = 256;
static constexpr int cBN = cB * cN;
#define PI_F 3.14159265358979323846f

__device__ __forceinline__ float2 cmul(float2 a, float2 b) {
    return make_float2(a.x*b.x - a.y*b.y, a.x*b.y + a.y*b.x);
}
__device__ __forceinline__ float2 cfma2(float2 a, float2 b, float2 acc) {
    acc.x += a.x*b.x - a.y*b.y;
    acc.y += a.x*b.y + a.y*b.x;
    return acc;
}
__device__ __forceinline__ float2 cneg(float2 a) { return make_float2(-a.x, -a.y); }

struct G4 { float2 ii, ij, ji, jj; };

__device__ __forceinline__ G4 givens_f(float al, float be, float ga) {
    float ra = (al + be) * (PI_F * 0.5f);
    float rs = (al - be) * (PI_F * 0.5f);
    float gm = ga * (PI_F * 0.5f);
    float sg, cg, sra, cra, srs, crs;
    sincosf(gm, &sg, &cg);
    sincosf(ra, &sra, &cra);
    sincosf(rs, &srs, &crs);
    G4 g;
    g.ii = make_float2( cra*cg, -sra*cg);
    g.ij = make_float2( crs*sg, -srs*sg);
    g.ji = make_float2(-crs*sg, -srs*sg);
    g.jj = make_float2( cra*cg,  sra*cg);
    return g;
}

__global__ void sentinel_kernel(float* out, int n, float v) {
    if (n > 0) out[0] = v;
    if (n > 1) out[1] = v;
}

// ---------------------------------------------------------------------------
// Weight convert: fp32 W -> f16. Layout: W16[m][65536], m={ev1,ev2,hp1,hp2}.
// ---------------------------------------------------------------------------
__global__ __launch_bounds__(256) void wcvt_kernel(
    const float* __restrict__ w0, const float* __restrict__ w1,
    const float* __restrict__ w2, const float* __restrict__ w3,
    _Float16* __restrict__ W16)
{
    int i = blockIdx.x * 256 + threadIdx.x;   // 0..65535
    const float* src[4] = {w0, w1, w2, w3};
    #pragma unroll
    for (int m = 0; m < 4; ++m)
        W16[(size_t)m*65536 + i] = (_Float16)src[m][i];
}

// ---------------------------------------------------------------------------
// SIREN (r15 col-ownership dataflow, 32-row blocks for 4 blocks/CU):
// Block = 32 rows x 256 cols, 8 waves; wave w owns cols [w*32, w*32+32)
// (2 nt-tiles) x 2 mt row-tiles. Grid (cBN/32, 2) = 2048 blocks -> 32
// waves/CU (HW max). LDS 17KB. launch_bounds(512,2): proven envelope.
// ---------------------------------------------------------------------------
__device__ __forceinline__ void stage_x16(const float* __restrict__ xrow0,
                                          _Float16* buf, int tid)
{
    const int row = tid >> 4;          // 0..31
    const int c0  = (tid & 15) * 16;   // 16 cols per thread
    const float4* src = (const float4*)(xrow0 + row*256 + c0);
    const int swz = (row & 7) << 4;
    #pragma unroll
    for (int j = 0; j < 2; ++j) {
        float4 p = src[2*j], q = src[2*j+1];
        f16x8 h;
        h[0]=(_Float16)p.x; h[1]=(_Float16)p.y; h[2]=(_Float16)p.z; h[3]=(_Float16)p.w;
        h[4]=(_Float16)q.x; h[5]=(_Float16)q.y; h[6]=(_Float16)q.z; h[7]=(_Float16)q.w;
        int off = (((c0 + j*8) * 2) ^ swz);
        *(f16x8*)((char*)buf + row*512 + off) = h;
    }
}

__device__ __forceinline__ void ld_a1(const _Float16* src, int k0, int lr, int kq,
                                      f16x8 ah[2])
{
    #pragma unroll
    for (int mt = 0; mt < 2; ++mt) {
        int row = mt*16 + lr;
        int off = ((k0*2 + kq*16) ^ ((row & 7) << 4));
        ah[mt] = *(const f16x8*)((const char*)src + row*512 + off);
    }
}

__device__ __forceinline__ void ld_w1(const _Float16* __restrict__ wP,
                                      int k0, int w, int lr, int kq, f16x8 bh[2])
{
    #pragma unroll
    for (int nt = 0; nt < 2; ++nt) {
        int col = w*32 + nt*16 + lr;
        bh[nt] = *(const f16x8*)(wP + col*256 + k0 + kq*8);
    }
}

__device__ __forceinline__ void do_mfma4(const f16x8 ah[2], const f16x8 bh[2],
                                         f32x4 acc[2][2])
{
    #pragma unroll
    for (int mt = 0; mt < 2; ++mt)
        #pragma unroll
        for (int nt = 0; nt < 2; ++nt)
            acc[mt][nt] = __builtin_amdgcn_mfma_f32_16x16x32_f16(ah[mt], bh[nt], acc[mt][nt], 0, 0, 0);
}

__device__ __forceinline__ void gemm32(const _Float16* aSrc,
                                       const _Float16* __restrict__ wP,
                                       int w, int lr, int kq, f32x4 acc[2][2])
{
    f16x8 ah[2];
    f16x8 b0[2], b1[2];
    ld_w1(wP, 0, w, lr, kq, b0);
    #pragma unroll
    for (int kk = 0; kk < 8; ++kk) {
        ld_a1(aSrc, kk*32, lr, kq, ah);
        if ((kk & 1) == 0) {
            if (kk < 7) ld_w1(wP, (kk+1)*32, w, lr, kq, b1);
            do_mfma4(ah, b0, acc);
        } else {
            if (kk < 7) ld_w1(wP, (kk+1)*32, w, lr, kq, b0);
            do_mfma4(ah, b1, acc);
        }
    }
}

__global__ __launch_bounds__(512, 2) void siren_mfma(
    const float* __restrict__ x, const _Float16* __restrict__ W16,
    const float* __restrict__ ev_b1, const float* __restrict__ ev_g,
    const float* __restrict__ ev_b2,
    const float* __restrict__ hp_b1, const float* __restrict__ hp_g,
    const float* __restrict__ hp_b2,
    const float* __restrict__ cheb,
    float* __restrict__ Pout, float2* __restrict__ DIAG)
{
    __shared__ _Float16 buf[32*256];   // 16 KB
    __shared__ float red[8][32];

    const int tid  = threadIdx.x;
    const int w    = tid >> 6;          // 0..7
    const int lane = tid & 63;
    const int lr   = lane & 15;
    const int kq   = lane >> 4;
    const size_t r0 = (size_t)blockIdx.x * 32;
    const int b   = (int)(r0 >> 12);
    const int net = blockIdx.y;         // 0 = EV, 1 = HP

    const _Float16* w1P = W16 + (size_t)(net*2 + 0)*65536;
    const _Float16* w2P = W16 + (size_t)(net*2 + 1)*65536;
    const float* b1 = net ? hp_b1 : ev_b1;
    const float* b2 = net ? hp_b2 : ev_b2;
    const float  g  = net ? hp_g[0] : ev_g[0];

    stage_x16(x + r0*256, buf, tid);
    __syncthreads();

    f32x4 acc[2][2];
    #pragma unroll
    for (int mt = 0; mt < 2; ++mt)
        #pragma unroll
        for (int nt = 0; nt < 2; ++nt) acc[mt][nt] = (f32x4)(0.f);
    gemm32(buf, w1P, w, lr, kq, acc);

    {   // layer-1 epilogue: sin + ScaleNorm -> act overwrites buf
        float bv[2] = { b1[w*32 + lr], b1[w*32 + 16 + lr] };
        float rn[2][4];
        #pragma unroll
        for (int mt = 0; mt < 2; ++mt)
            #pragma unroll
            for (int r = 0; r < 4; ++r) {
                float s = 0.f;
                #pragma unroll
                for (int nt = 0; nt < 2; ++nt) {
                    float v = __sinf(acc[mt][nt][r] + bv[nt]);
                    s += v*v;
                }
                rn[mt][r] = s;
            }
        #pragma unroll
        for (int mk = 1; mk < 16; mk <<= 1)
            #pragma unroll
            for (int mt = 0; mt < 2; ++mt)
                #pragma unroll
                for (int r = 0; r < 4; ++r) rn[mt][r] += __shfl_xor(rn[mt][r], mk);
        if (lr == 0)
            #pragma unroll
            for (int mt = 0; mt < 2; ++mt)
                #pragma unroll
                for (int r = 0; r < 4; ++r) red[w][mt*16 + kq*4 + r] = rn[mt][r];
        __syncthreads();   // red visible AND all gemm-L1 buf reads done
        #pragma unroll
        for (int mt = 0; mt < 2; ++mt)
            #pragma unroll
            for (int r = 0; r < 4; ++r) {
                int row = mt*16 + kq*4 + r;
                float tot = 0.f;
                #pragma unroll
                for (int ww = 0; ww < 8; ++ww) tot += red[ww][row];
                float sc = g / fmaxf(sqrtf(tot), 1e-5f);
                int swz = (row & 7) << 4;
                #pragma unroll
                for (int nt = 0; nt < 2; ++nt) {
                    float v = __sinf(acc[mt][nt][r] + bv[nt]) * sc;
                    int col = w*32 + nt*16 + lr;
                    *(_Float16*)((char*)buf + row*512 + ((col*2) ^ swz)) = (_Float16)v;
                }
            }
    }
    __syncthreads();

    #pragma unroll
    for (int mt = 0; mt < 2; ++mt)
        #pragma unroll
        for (int nt = 0; nt < 2; ++nt) acc[mt][nt] = (f32x4)(0.f);
    gemm32(buf, w2P, w, lr, kq, acc);

    if (net == 0) {   // eig -> DIAG
        float bv[2] = { b2[w*32 + lr], b2[w*32 + 16 + lr] };
        float es[2][4];
        #pragma unroll
        for (int mt = 0; mt < 2; ++mt)
            #pragma unroll
            for (int r = 0; r < 4; ++r) {
                float s = 0.f;
                #pragma unroll
                for (int nt = 0; nt < 2; ++nt) s += __sinf(acc[mt][nt][r] + bv[nt]);
                es[mt][r] = s;
            }
        #pragma unroll
        for (int mk = 1; mk < 16; mk <<= 1)
            #pragma unroll
            for (int mt = 0; mt < 2; ++mt)
                #pragma unroll
                for (int r = 0; r < 4; ++r) es[mt][r] += __shfl_xor(es[mt][r], mk);
        if (lr == 0)
            #pragma unroll
            for (int mt = 0; mt < 2; ++mt)
                #pragma unroll
                for (int r = 0; r < 4; ++r) red[w][mt*16 + kq*4 + r] = es[mt][r];
        __syncthreads();
        if (tid < 32) {
            int row = tid;
            float tot = 0.f;
            #pragma unroll
            for (int ww = 0; ww < 8; ++ww) tot += red[ww][row];
            float ev = tot * (1.f/256.f);
            float dmp[9];
            {
                const double c = 3.14159265358979323846 / 10.0;
                double sc = sin(c), cc = cos(c);
                dmp[0] = 1.f;
                for (int k = 1; k < 9; ++k)
                    dmp[k] = (float)(((10.0 - k) * sc * cos(k*c) + cc * sin(k*c)) / (10.0 * sc));
            }
            const float* cf = cheb + b*9;
            float t0 = 1.f, t1 = ev;
            float filt = cf[0] + ev * cf[1] * dmp[1];
            #pragma unroll
            for (int k = 2; k < 9; ++k) {
                float t2 = 2.f*ev*t1 - t0;
                filt += t2 * cf[k] * dmp[k];
                t0 = t1; t1 = t2;
            }
            float sp, cp;
            sincosf(PI_F * ev, &sp, &cp);
            DIAG[r0 + row] = make_float2(filt*cp, filt*sp);
        }
    } else {          // pool -> Pout
        __syncthreads();   // all gemm-L2 buf reads done before overwrite
        float bv[2] = { b2[w*32 + lr], b2[w*32 + 16 + lr] };
        #pragma unroll
        for (int mt = 0; mt < 2; ++mt)
            #pragma unroll
            for (int r = 0; r < 4; ++r) {
                int row = mt*16 + kq*4 + r;
                int swz = (row & 7) << 4;
                #pragma unroll
                for (int nt = 0; nt < 2; ++nt) {
                    float v = __sinf(acc[mt][nt][r] + bv[nt]);
                    int col = w*32 + nt*16 + lr;
                    *(_Float16*)((char*)buf + row*512 + ((col*2) ^ swz)) = (_Float16)v;
                }
            }
        __syncthreads();
        if (tid < 192) {   // AdaptiveAvgPool1d(6), torch bins; flat [B][6N]
            const int sb[6] = {0, 42, 85, 128, 170, 213};
            const int eb[6] = {43, 86, 128, 171, 214, 256};
            const float inv[6] = {1.f/43.f, 1.f/44.f, 1.f/43.f, 1.f/43.f, 1.f/44.f, 1.f/43.f};
            int row = tid / 6, q = tid - row*6;
            int swz = (row & 7) << 4;
            float s = 0.f;
            for (int c = sb[q]; c < eb[q]; ++c)
                s += (float)(*(const _Float16*)((const char*)buf + row*512 + ((c*2) ^ swz)));
            int nn = (int)(r0 & 4095) + row;
            Pout[(size_t)b*6*cN + nn*6 + q] = s * inv[q];
        }
    }
}

// ---------------------------------------------------------------------------
// DHHP: 9-band operator T = L' U' D L U composed in-block (32 lanes), then
// float4 9-tap stencil over a 32-row x 256-col tile.
// ---------------------------------------------------------------------------
__global__ __launch_bounds__(256) void dhhp_stencil(
    const float* __restrict__ x, const float* __restrict__ P,
    const float2* __restrict__ DIAG, float* __restrict__ outf,
    unsigned long long out_floats, int mode)
{
    __shared__ float  xsr[40*256];
    __shared__ G4 uG[41], lG[41];
    __shared__ float2 cDg[40];
    __shared__ float2 cT[32][9];

    const int tid = threadIdx.x;
    const int n0 = blockIdx.x * 32;
    const int b  = blockIdx.y;
    const size_t bbase = (size_t)b * cN;
    const int b6 = b * 6 * cN;
    const float2 z2 = make_float2(0.f, 0.f);
    const int jb = n0 - 5;

    for (int idx = tid; idx < 40*64; idx += 256) {   // float4 staging
        int r = idx >> 6, d4 = idx & 63;
        int m = n0 - 4 + r;
        float4 v = make_float4(0.f, 0.f, 0.f, 0.f);
        if (m >= 0 && m < cN) v = *(const float4*)(x + (bbase + m)*cD + d4*4);
        *(float4*)(xsr + r*256 + d4*4) = v;
    }
    if (tid < 82) {
        int t = (tid < 41) ? tid : tid - 41;
        int j = jb + t;
        G4 g; g.ii = g.ij = g.ji = g.jj = z2;
        if (j >= 0 && j <= cN-2) {
            if (tid < 41) g = givens_f(P[b6+3*cN+j], P[b6+4*cN+j], P[b6+5*cN+j]);   // u[j]
            else          g = givens_f(P[b6+j+1],    P[b6+cN+j+1], P[b6+2*cN+j+1]); // l[j]
        }
        if (tid < 41) uG[t] = g; else lG[t] = g;
    } else if (tid < 122) {
        int t = tid - 82;
        int m = n0 - 4 + t;
        cDg[t] = (m >= 0 && m < cN) ? DIAG[bbase + m] : z2;
    }
    __syncthreads();

    if (tid < 32) {
        const int m = n0 + tid;
        auto scoef = [&](int s, int rr, float2& A, float2& B, float2& C) {
            A = z2; B = z2; C = z2;
            if (rr < 0 || rr >= cN) return;
            if (s == 1) {
                if (rr == 0)         { G4 u0 = uG[0-jb]; B = u0.ii; C = u0.ij; }
                else if (rr == cN-1) { G4 up = uG[rr-1-jb]; A = up.ji; B = up.jj; }
                else { G4 up = uG[rr-1-jb], uc = uG[rr-jb];
                       A = up.ji; B = cmul(up.jj, uc.ii); C = cmul(up.jj, uc.ij); }
            } else if (s == 2) {
                if (rr == 0)         { G4 l0 = lG[0-jb]; B = l0.ii; C = l0.ij; }
                else if (rr == cN-1) { G4 lp = lG[rr-1-jb]; A = lp.ji; B = lp.jj; }
                else { G4 lp = lG[rr-1-jb], lc = lG[rr-jb];
                       A = cmul(lc.ii, lp.ji); B = cmul(lc.ii, lp.jj); C = lc.ij; }
            } else if (s == 3) {
                if (rr == 0)         { G4 u0 = uG[0-jb]; B = u0.jj; C = cneg(u0.ij); }
                else if (rr == cN-1) { G4 up = uG[rr-1-jb]; A = cneg(up.ji); B = up.ii; }
                else { G4 up = uG[rr-1-jb], uc = uG[rr-jb];
                       A = cneg(up.ji); B = cmul(up.ii, uc.jj); C = cneg(cmul(up.ii, uc.ij)); }
            } else {
                if (rr == 0)         { G4 l0 = lG[0-jb]; B = l0.jj; C = cneg(l0.ij); }
                else if (rr == cN-1) { G4 lp = lG[rr-1-jb]; A = cneg(lp.ji); B = lp.ii; }
                else { G4 lp = lG[rr-1-jb], lc = lG[rr-jb];
                       A = cneg(cmul(lc.jj, lp.ji)); B = cmul(lc.jj, lp.ii); C = cneg(lc.ij); }
            }
        };

        float2 wv[9], nw[9];
        #pragma unroll
        for (int k = 0; k < 9; ++k) wv[k] = z2;
        {
            float2 A, B, C; scoef(4, m, A, B, C);
            wv[3] = A; wv[4] = B; wv[5] = C;
        }
        #pragma unroll
        for (int k = 0; k < 9; ++k) nw[k] = z2;
        #pragma unroll
        for (int i = 3; i <= 5; ++i) {
            float2 A, B, C; scoef(3, m + i - 4, A, B, C);
            nw[i-1] = cfma2(wv[i], A, nw[i-1]);
            nw[i]   = cfma2(wv[i], B, nw[i]);
            nw[i+1] = cfma2(wv[i], C, nw[i+1]);
        }
        #pragma unroll
        for (int k = 0; k < 9; ++k) wv[k] = nw[k];
        #pragma unroll
        for (int k = 2; k <= 6; ++k) wv[k] = cmul(wv[k], cDg[tid + k]);
        #pragma unroll
        for (int k = 0; k < 9; ++k) nw[k] = z2;
        #pragma unroll
        for (int i = 2; i <= 6; ++i) {
            float2 A, B, C; scoef(2, m + i - 4, A, B, C);
            nw[i-1] = cfma2(wv[i], A, nw[i-1]);
            nw[i]   = cfma2(wv[i], B, nw[i]);
            nw[i+1] = cfma2(wv[i], C, nw[i+1]);
        }
        #pragma unroll
        for (int k = 0; k < 9; ++k) wv[k] = nw[k];
        #pragma unroll
        for (int k = 0; k < 9; ++k) nw[k] = z2;
        #pragma unroll
        for (int i = 1; i <= 7; ++i) {
            float2 A, B, C; scoef(1, m + i - 4, A, B, C);
            nw[i-1] = cfma2(wv[i], A, nw[i-1]);
            nw[i]   = cfma2(wv[i], B, nw[i]);
            nw[i+1] = cfma2(wv[i], C, nw[i+1]);
        }
        #pragma unroll
        for (int k = 0; k < 9; ++k) cT[tid][k] = nw[k];
    }
    __syncthreads();

    for (int idx = tid; idx < 32*64; idx += 256) {   // 8 float4 outputs/thread
        int r = idx >> 6, d4 = idx & 63;
        float4 ox = make_float4(0.f, 0.f, 0.f, 0.f);
        float4 oy = make_float4(0.f, 0.f, 0.f, 0.f);
        #pragma unroll
        for (int j = 0; j < 9; ++j) {
            float4 xv = *(const float4*)(xsr + (r + j)*256 + d4*4);
            float2 t = cT[r][j];
            ox.x = fmaf(t.x, xv.x, ox.x); ox.y = fmaf(t.x, xv.y, ox.y);
            ox.z = fmaf(t.x, xv.z, ox.z); ox.w = fmaf(t.x, xv.w, ox.w);
            oy.x = fmaf(t.y, xv.x, oy.x); oy.y = fmaf(t.y, xv.y, oy.y);
            oy.z = fmaf(t.y, xv.z, oy.z); oy.w = fmaf(t.y, xv.w, oy.w);
        }
        unsigned long long ci = (unsigned long long)((bbase + n0 + r)*(size_t)cD + d4*4);
        if (mode == 0) {
            if (ci + 4ULL <= out_floats) *(float4*)(outf + ci) = ox;
        } else {
            if (2ULL*(ci + 4ULL) <= out_floats) {
                float2* o2 = (float2*)outf + ci;
                o2[0] = make_float2(ox.x, oy.x);
                o2[1] = make_float2(ox.y, oy.y);
                o2[2] = make_float2(ox.z, oy.z);
                o2[3] = make_float2(ox.w, oy.w);
            }
        }
    }
}

// ---------------------------------------------------------------------------
extern "C" void kernel_launch(void* const* d_in, const int* in_sizes, int n_in,
                              void* d_out, int out_size, void* d_ws, size_t ws_size,
                              hipStream_t stream)
{
    const int expect[12] = { cBN*cD, cD*cD, cD, 1, cD*cD, cD,
                             cD*cD, cD, 1, cD*cD, cD, cB*9 };
    bool ok = (n_in == 12);
    if (ok) for (int i = 0; i < 12; ++i) ok = ok && (in_sizes[i] == expect[i]);
    if (!ok) {
        sentinel_kernel<<<1, 1, 0, stream>>>((float*)d_out, out_size, 1.0e6f);
        return;
    }
    const size_t pBytes = (size_t)cB * 6 * cN * sizeof(float);       // 768 KB
    const size_t dBytes = (size_t)cBN * sizeof(float2);              // 256 KB
    const size_t wBytes = (size_t)4 * 65536 * sizeof(_Float16);      // 512 KB
    if (d_ws == nullptr || ws_size < pBytes + dBytes + wBytes) {
        sentinel_kernel<<<1, 1, 0, stream>>>((float*)d_out, out_size, 2.0e6f);
        return;
    }
    int mode;
    if (out_size == cBN * cD)          mode = 0;
    else if (out_size == 2 * cBN * cD) mode = 1;
    else {
        sentinel_kernel<<<1, 1, 0, stream>>>((float*)d_out, out_size, 3.0e6f);
        return;
    }

    const float* x     = (const float*)d_in[0];
    const float* ev_w1 = (const float*)d_in[1];
    const float* ev_b1 = (const float*)d_in[2];
    const float* ev_g  = (const float*)d_in[3];
    const float* ev_w2 = (const float*)d_in[4];
    const float* ev_b2 = (const float*)d_in[5];
    const float* hp_w1 = (const float*)d_in[6];
    const float* hp_b1 = (const float*)d_in[7];
    const float* hp_g  = (const float*)d_in[8];
    const float* hp_w2 = (const float*)d_in[9];
    const float* hp_b2 = (const float*)d_in[10];
    const float* cheb  = (const float*)d_in[11];

    float*     P    = (float*)d_ws;
    float2*    DIAG = (float2*)((char*)d_ws + pBytes);
    _Float16*  W16  = (_Float16*)((char*)d_ws + pBytes + dBytes);

    wcvt_kernel<<<dim3(256), 256, 0, stream>>>(ev_w1, ev_w2, hp_w1, hp_w2, W16);
    siren_mfma<<<dim3(cBN/32, 2), 512, 0, stream>>>(x, W16, ev_b1, ev_g, ev_b2,
                                                    hp_b1, hp_g, hp_b2, cheb, P, DIAG);
    dhhp_stencil<<<dim3(cN/32, cB), 256, 0, stream>>>(x, P, DIAG, (float*)d_out,
                                                      (unsigned long long)out_size,
                                                      mode);
}

// Round 18
// 83.317 us; speedup vs baseline: 2.1029x; 1.2610x over previous
//
#include <hip/hip_runtime.h>
#include <math.h>

typedef __attribute__((ext_vector_type(8))) _Float16 f16x8;
typedef __attribute__((ext_vector_type(4))) float    f32x4;

static constexpr int cB  = 8;
static constexpr int cN  = 4096;
static constexpr int cD  = 256;
static constexpr int cBN = cB * cN;
#define PI_F 3.14159265358979323846f

__device__ __forceinline__ float2 cmul(float2 a, float2 b) {
    return make_float2(a.x*b.x - a.y*b.y, a.x*b.y + a.y*b.x);
}
__device__ __forceinline__ float2 cfma2(float2 a, float2 b, float2 acc) {
    acc.x += a.x*b.x - a.y*b.y;
    acc.y += a.x*b.y + a.y*b.x;
    return acc;
}
__device__ __forceinline__ float2 cneg(float2 a) { return make_float2(-a.x, -a.y); }

struct G4 { float2 ii, ij, ji, jj; };

__device__ __forceinline__ G4 givens_f(float al, float be, float ga) {
    float ra = (al + be) * (PI_F * 0.5f);
    float rs = (al - be) * (PI_F * 0.5f);
    float gm = ga * (PI_F * 0.5f);
    float sg, cg, sra, cra, srs, crs;
    sincosf(gm, &sg, &cg);
    sincosf(ra, &sra, &cra);
    sincosf(rs, &srs, &crs);
    G4 g;
    g.ii = make_float2( cra*cg, -sra*cg);
    g.ij = make_float2( crs*sg, -srs*sg);
    g.ji = make_float2(-crs*sg, -srs*sg);
    g.jj = make_float2( cra*cg,  sra*cg);
    return g;
}

__global__ void sentinel_kernel(float* out, int n, float v) {
    if (n > 0) out[0] = v;
    if (n > 1) out[1] = v;
}

// ---------------------------------------------------------------------------
// Weight convert: fp32 W -> f16. Layout: W16[m][65536], m={ev1,ev2,hp1,hp2}.
// ---------------------------------------------------------------------------
__global__ __launch_bounds__(256) void wcvt_kernel(
    const float* __restrict__ w0, const float* __restrict__ w1,
    const float* __restrict__ w2, const float* __restrict__ w3,
    _Float16* __restrict__ W16)
{
    int i = blockIdx.x * 256 + threadIdx.x;   // 0..65535
    const float* src[4] = {w0, w1, w2, w3};
    #pragma unroll
    for (int m = 0; m < 4; ++m)
        W16[(size_t)m*65536 + i] = (_Float16)src[m][i];
}

// ---------------------------------------------------------------------------
// SIREN (r15 final config — best measured): pure f16 x f16 MFMA; EV/HP nets
// split across blockIdx.y. Block = 64 rows x 256 cols, 8 waves; wave w owns
// cols [w*32, w*32+32). ONE 32KB LDS buffer. launch_bounds(512,2).
// Lessons pinned: (r8/r11) launch_bounds 2nd arg != waves/EU on this
// toolchain — only (512,2) is spill-free; (r14) barrier-crossing values are
// rematerialized at VGPR=64; (r16) row-ownership kills weight reuse;
// (r17) occupancy is pinned ~37% regardless of block size/resources.
// ---------------------------------------------------------------------------
__device__ __forceinline__ void stage_x16(const float* __restrict__ xrow0,
                                          _Float16* buf, int tid)
{
    const int row = tid >> 3;          // 0..63
    const int c0  = (tid & 7) * 32;    // 32 cols per thread
    const float4* src = (const float4*)(xrow0 + row*256 + c0);
    const int swz = (row & 7) << 4;
    #pragma unroll
    for (int j = 0; j < 4; ++j) {
        float4 p = src[2*j], q = src[2*j+1];
        f16x8 h;
        h[0]=(_Float16)p.x; h[1]=(_Float16)p.y; h[2]=(_Float16)p.z; h[3]=(_Float16)p.w;
        h[4]=(_Float16)q.x; h[5]=(_Float16)q.y; h[6]=(_Float16)q.z; h[7]=(_Float16)q.w;
        int off = (((c0 + j*8) * 2) ^ swz);
        *(f16x8*)((char*)buf + row*512 + off) = h;
    }
}

__device__ __forceinline__ void ld_a1(const _Float16* src, int k0, int lr, int kq,
                                      f16x8 ah[4])
{
    #pragma unroll
    for (int mt = 0; mt < 4; ++mt) {
        int row = mt*16 + lr;
        int off = ((k0*2 + kq*16) ^ ((row & 7) << 4));
        ah[mt] = *(const f16x8*)((const char*)src + row*512 + off);
    }
}

__device__ __forceinline__ void ld_w1(const _Float16* __restrict__ wP,
                                      int k0, int w, int lr, int kq, f16x8 bh[2])
{
    #pragma unroll
    for (int nt = 0; nt < 2; ++nt) {
        int col = w*32 + nt*16 + lr;
        bh[nt] = *(const f16x8*)(wP + col*256 + k0 + kq*8);
    }
}

__device__ __forceinline__ void do_mfma8(const f16x8 ah[4], const f16x8 bh[2],
                                         f32x4 acc[4][2])
{
    #pragma unroll
    for (int mt = 0; mt < 4; ++mt)
        #pragma unroll
        for (int nt = 0; nt < 2; ++nt)
            acc[mt][nt] = __builtin_amdgcn_mfma_f32_16x16x32_f16(ah[mt], bh[nt], acc[mt][nt], 0, 0, 0);
}

__device__ __forceinline__ void gemm32(const _Float16* aSrc,
                                       const _Float16* __restrict__ wP,
                                       int w, int lr, int kq, f32x4 acc[4][2])
{
    f16x8 ah[4];
    f16x8 b0[2], b1[2];
    ld_w1(wP, 0, w, lr, kq, b0);
    #pragma unroll
    for (int kk = 0; kk < 8; ++kk) {
        ld_a1(aSrc, kk*32, lr, kq, ah);
        if ((kk & 1) == 0) {
            if (kk < 7) ld_w1(wP, (kk+1)*32, w, lr, kq, b1);
            do_mfma8(ah, b0, acc);
        } else {
            if (kk < 7) ld_w1(wP, (kk+1)*32, w, lr, kq, b0);
            do_mfma8(ah, b1, acc);
        }
    }
}

__global__ __launch_bounds__(512, 2) void siren_mfma(
    const float* __restrict__ x, const _Float16* __restrict__ W16,
    const float* __restrict__ ev_b1, const float* __restrict__ ev_g,
    const float* __restrict__ ev_b2,
    const float* __restrict__ hp_b1, const float* __restrict__ hp_g,
    const float* __restrict__ hp_b2,
    const float* __restrict__ cheb,
    float* __restrict__ Pout, float2* __restrict__ DIAG)
{
    __shared__ _Float16 buf[64*256];
    __shared__ float red[8][64];

    const int tid  = threadIdx.x;
    const int w    = tid >> 6;          // 0..7
    const int lane = tid & 63;
    const int lr   = lane & 15;
    const int kq   = lane >> 4;
    const size_t r0 = (size_t)blockIdx.x * 64;
    const int b   = (int)(r0 >> 12);
    const int net = blockIdx.y;         // 0 = EV, 1 = HP

    const _Float16* w1P = W16 + (size_t)(net*2 + 0)*65536;
    const _Float16* w2P = W16 + (size_t)(net*2 + 1)*65536;
    const float* b1 = net ? hp_b1 : ev_b1;
    const float* b2 = net ? hp_b2 : ev_b2;
    const float  g  = net ? hp_g[0] : ev_g[0];

    stage_x16(x + r0*256, buf, tid);
    __syncthreads();

    f32x4 acc[4][2];
    #pragma unroll
    for (int mt = 0; mt < 4; ++mt)
        #pragma unroll
        for (int nt = 0; nt < 2; ++nt) acc[mt][nt] = (f32x4)(0.f);
    gemm32(buf, w1P, w, lr, kq, acc);

    {   // layer-1 epilogue: sin + ScaleNorm -> act overwrites buf
        float bv[2] = { b1[w*32 + lr], b1[w*32 + 16 + lr] };
        float rn[4][4];
        #pragma unroll
        for (int mt = 0; mt < 4; ++mt)
            #pragma unroll
            for (int r = 0; r < 4; ++r) {
                float s = 0.f;
                #pragma unroll
                for (int nt = 0; nt < 2; ++nt) {
                    float v = __sinf(acc[mt][nt][r] + bv[nt]);
                    s += v*v;
                }
                rn[mt][r] = s;
            }
        #pragma unroll
        for (int mk = 1; mk < 16; mk <<= 1)
            #pragma unroll
            for (int mt = 0; mt < 4; ++mt)
                #pragma unroll
                for (int r = 0; r < 4; ++r) rn[mt][r] += __shfl_xor(rn[mt][r], mk);
        if (lr == 0)
            #pragma unroll
            for (int mt = 0; mt < 4; ++mt)
                #pragma unroll
                for (int r = 0; r < 4; ++r) red[w][mt*16 + kq*4 + r] = rn[mt][r];
        __syncthreads();   // red visible AND all gemm-L1 buf reads done
        #pragma unroll
        for (int mt = 0; mt < 4; ++mt)
            #pragma unroll
            for (int r = 0; r < 4; ++r) {
                int row = mt*16 + kq*4 + r;
                float tot = 0.f;
                #pragma unroll
                for (int ww = 0; ww < 8; ++ww) tot += red[ww][row];
                float sc = g / fmaxf(sqrtf(tot), 1e-5f);
                int swz = (row & 7) << 4;
                #pragma unroll
                for (int nt = 0; nt < 2; ++nt) {
                    float v = __sinf(acc[mt][nt][r] + bv[nt]) * sc;
                    int col = w*32 + nt*16 + lr;
                    *(_Float16*)((char*)buf + row*512 + ((col*2) ^ swz)) = (_Float16)v;
                }
            }
    }
    __syncthreads();

    #pragma unroll
    for (int mt = 0; mt < 4; ++mt)
        #pragma unroll
        for (int nt = 0; nt < 2; ++nt) acc[mt][nt] = (f32x4)(0.f);
    gemm32(buf, w2P, w, lr, kq, acc);

    if (net == 0) {   // eig -> DIAG
        float bv[2] = { b2[w*32 + lr], b2[w*32 + 16 + lr] };
        float es[4][4];
        #pragma unroll
        for (int mt = 0; mt < 4; ++mt)
            #pragma unroll
            for (int r = 0; r < 4; ++r) {
                float s = 0.f;
                #pragma unroll
                for (int nt = 0; nt < 2; ++nt) s += __sinf(acc[mt][nt][r] + bv[nt]);
                es[mt][r] = s;
            }
        #pragma unroll
        for (int mk = 1; mk < 16; mk <<= 1)
            #pragma unroll
            for (int mt = 0; mt < 4; ++mt)
                #pragma unroll
                for (int r = 0; r < 4; ++r) es[mt][r] += __shfl_xor(es[mt][r], mk);
        if (lr == 0)
            #pragma unroll
            for (int mt = 0; mt < 4; ++mt)
                #pragma unroll
                for (int r = 0; r < 4; ++r) red[w][mt*16 + kq*4 + r] = es[mt][r];
        __syncthreads();
        if (tid < 64) {
            int row = tid;
            float tot = 0.f;
            #pragma unroll
            for (int ww = 0; ww < 8; ++ww) tot += red[ww][row];
            float ev = tot * (1.f/256.f);
            float dmp[9];
            {
                const double c = 3.14159265358979323846 / 10.0;
                double sc = sin(c), cc = cos(c);
                dmp[0] = 1.f;
                for (int k = 1; k < 9; ++k)
                    dmp[k] = (float)(((10.0 - k) * sc * cos(k*c) + cc * sin(k*c)) / (10.0 * sc));
            }
            const float* cf = cheb + b*9;
            float t0 = 1.f, t1 = ev;
            float filt = cf[0] + ev * cf[1] * dmp[1];
            #pragma unroll
            for (int k = 2; k < 9; ++k) {
                float t2 = 2.f*ev*t1 - t0;
                filt += t2 * cf[k] * dmp[k];
                t0 = t1; t1 = t2;
            }
            float sp, cp;
            sincosf(PI_F * ev, &sp, &cp);
            DIAG[r0 + row] = make_float2(filt*cp, filt*sp);
        }
    } else {          // pool -> Pout
        __syncthreads();   // all gemm-L2 buf reads done before overwrite
        float bv[2] = { b2[w*32 + lr], b2[w*32 + 16 + lr] };
        #pragma unroll
        for (int mt = 0; mt < 4; ++mt)
            #pragma unroll
            for (int r = 0; r < 4; ++r) {
                int row = mt*16 + kq*4 + r;
                int swz = (row & 7) << 4;
                #pragma unroll
                for (int nt = 0; nt < 2; ++nt) {
                    float v = __sinf(acc[mt][nt][r] + bv[nt]);
                    int col = w*32 + nt*16 + lr;
                    *(_Float16*)((char*)buf + row*512 + ((col*2) ^ swz)) = (_Float16)v;
                }
            }
        __syncthreads();
        if (tid < 384) {   // AdaptiveAvgPool1d(6), torch bins; flat [B][6N]
            const int sb[6] = {0, 42, 85, 128, 170, 213};
            const int eb[6] = {43, 86, 128, 171, 214, 256};
            const float inv[6] = {1.f/43.f, 1.f/44.f, 1.f/43.f, 1.f/43.f, 1.f/44.f, 1.f/43.f};
            int row = tid / 6, q = tid - row*6;
            int swz = (row & 7) << 4;
            float s = 0.f;
            for (int c = sb[q]; c < eb[q]; ++c)
                s += (float)(*(const _Float16*)((const char*)buf + row*512 + ((c*2) ^ swz)));
            int nn = (int)(r0 & 4095) + row;
            Pout[(size_t)b*6*cN + nn*6 + q] = s * inv[q];
        }
    }
}

// ---------------------------------------------------------------------------
// DHHP: 9-band operator T = L' U' D L U composed in-block (32 lanes), then
// float4 9-tap stencil over a 32-row x 256-col tile.
// ---------------------------------------------------------------------------
__global__ __launch_bounds__(256) void dhhp_stencil(
    const float* __restrict__ x, const float* __restrict__ P,
    const float2* __restrict__ DIAG, float* __restrict__ outf,
    unsigned long long out_floats, int mode)
{
    __shared__ float  xsr[40*256];
    __shared__ G4 uG[41], lG[41];
    __shared__ float2 cDg[40];
    __shared__ float2 cT[32][9];

    const int tid = threadIdx.x;
    const int n0 = blockIdx.x * 32;
    const int b  = blockIdx.y;
    const size_t bbase = (size_t)b * cN;
    const int b6 = b * 6 * cN;
    const float2 z2 = make_float2(0.f, 0.f);
    const int jb = n0 - 5;

    for (int idx = tid; idx < 40*64; idx += 256) {   // float4 staging
        int r = idx >> 6, d4 = idx & 63;
        int m = n0 - 4 + r;
        float4 v = make_float4(0.f, 0.f, 0.f, 0.f);
        if (m >= 0 && m < cN) v = *(const float4*)(x + (bbase + m)*cD + d4*4);
        *(float4*)(xsr + r*256 + d4*4) = v;
    }
    if (tid < 82) {
        int t = (tid < 41) ? tid : tid - 41;
        int j = jb + t;
        G4 g; g.ii = g.ij = g.ji = g.jj = z2;
        if (j >= 0 && j <= cN-2) {
            if (tid < 41) g = givens_f(P[b6+3*cN+j], P[b6+4*cN+j], P[b6+5*cN+j]);   // u[j]
            else          g = givens_f(P[b6+j+1],    P[b6+cN+j+1], P[b6+2*cN+j+1]); // l[j]
        }
        if (tid < 41) uG[t] = g; else lG[t] = g;
    } else if (tid < 122) {
        int t = tid - 82;
        int m = n0 - 4 + t;
        cDg[t] = (m >= 0 && m < cN) ? DIAG[bbase + m] : z2;
    }
    __syncthreads();

    if (tid < 32) {
        const int m = n0 + tid;
        auto scoef = [&](int s, int rr, float2& A, float2& B, float2& C) {
            A = z2; B = z2; C = z2;
            if (rr < 0 || rr >= cN) return;
            if (s == 1) {
                if (rr == 0)         { G4 u0 = uG[0-jb]; B = u0.ii; C = u0.ij; }
                else if (rr == cN-1) { G4 up = uG[rr-1-jb]; A = up.ji; B = up.jj; }
                else { G4 up = uG[rr-1-jb], uc = uG[rr-jb];
                       A = up.ji; B = cmul(up.jj, uc.ii); C = cmul(up.jj, uc.ij); }
            } else if (s == 2) {
                if (rr == 0)         { G4 l0 = lG[0-jb]; B = l0.ii; C = l0.ij; }
                else if (rr == cN-1) { G4 lp = lG[rr-1-jb]; A = lp.ji; B = lp.jj; }
                else { G4 lp = lG[rr-1-jb], lc = lG[rr-jb];
                       A = cmul(lc.ii, lp.ji); B = cmul(lc.ii, lp.jj); C = lc.ij; }
            } else if (s == 3) {
                if (rr == 0)         { G4 u0 = uG[0-jb]; B = u0.jj; C = cneg(u0.ij); }
                else if (rr == cN-1) { G4 up = uG[rr-1-jb]; A = cneg(up.ji); B = up.ii; }
                else { G4 up = uG[rr-1-jb], uc = uG[rr-jb];
                       A = cneg(up.ji); B = cmul(up.ii, uc.jj); C = cneg(cmul(up.ii, uc.ij)); }
            } else {
                if (rr == 0)         { G4 l0 = lG[0-jb]; B = l0.jj; C = cneg(l0.ij); }
                else if (rr == cN-1) { G4 lp = lG[rr-1-jb]; A = cneg(lp.ji); B = lp.ii; }
                else { G4 lp = lG[rr-1-jb], lc = lG[rr-jb];
                       A = cneg(cmul(lc.jj, lp.ji)); B = cmul(lc.jj, lp.ii); C = cneg(lc.ij); }
            }
        };

        float2 wv[9], nw[9];
        #pragma unroll
        for (int k = 0; k < 9; ++k) wv[k] = z2;
        {
            float2 A, B, C; scoef(4, m, A, B, C);
            wv[3] = A; wv[4] = B; wv[5] = C;
        }
        #pragma unroll
        for (int k = 0; k < 9; ++k) nw[k] = z2;
        #pragma unroll
        for (int i = 3; i <= 5; ++i) {
            float2 A, B, C; scoef(3, m + i - 4, A, B, C);
            nw[i-1] = cfma2(wv[i], A, nw[i-1]);
            nw[i]   = cfma2(wv[i], B, nw[i]);
            nw[i+1] = cfma2(wv[i], C, nw[i+1]);
        }
        #pragma unroll
        for (int k = 0; k < 9; ++k) wv[k] = nw[k];
        #pragma unroll
        for (int k = 2; k <= 6; ++k) wv[k] = cmul(wv[k], cDg[tid + k]);
        #pragma unroll
        for (int k = 0; k < 9; ++k) nw[k] = z2;
        #pragma unroll
        for (int i = 2; i <= 6; ++i) {
            float2 A, B, C; scoef(2, m + i - 4, A, B, C);
            nw[i-1] = cfma2(wv[i], A, nw[i-1]);
            nw[i]   = cfma2(wv[i], B, nw[i]);
            nw[i+1] = cfma2(wv[i], C, nw[i+1]);
        }
        #pragma unroll
        for (int k = 0; k < 9; ++k) wv[k] = nw[k];
        #pragma unroll
        for (int k = 0; k < 9; ++k) nw[k] = z2;
        #pragma unroll
        for (int i = 1; i <= 7; ++i) {
            float2 A, B, C; scoef(1, m + i - 4, A, B, C);
            nw[i-1] = cfma2(wv[i], A, nw[i-1]);
            nw[i]   = cfma2(wv[i], B, nw[i]);
            nw[i+1] = cfma2(wv[i], C, nw[i+1]);
        }
        #pragma unroll
        for (int k = 0; k < 9; ++k) cT[tid][k] = nw[k];
    }
    __syncthreads();

    for (int idx = tid; idx < 32*64; idx += 256) {   // 8 float4 outputs/thread
        int r = idx >> 6, d4 = idx & 63;
        float4 ox = make_float4(0.f, 0.f, 0.f, 0.f);
        float4 oy = make_float4(0.f, 0.f, 0.f, 0.f);
        #pragma unroll
        for (int j = 0; j < 9; ++j) {
            float4 xv = *(const float4*)(xsr + (r + j)*256 + d4*4);
            float2 t = cT[r][j];
            ox.x = fmaf(t.x, xv.x, ox.x); ox.y = fmaf(t.x, xv.y, ox.y);
            ox.z = fmaf(t.x, xv.z, ox.z); ox.w = fmaf(t.x, xv.w, ox.w);
            oy.x = fmaf(t.y, xv.x, oy.x); oy.y = fmaf(t.y, xv.y, oy.y);
            oy.z = fmaf(t.y, xv.z, oy.z); oy.w = fmaf(t.y, xv.w, oy.w);
        }
        unsigned long long ci = (unsigned long long)((bbase + n0 + r)*(size_t)cD + d4*4);
        if (mode == 0) {
            if (ci + 4ULL <= out_floats) *(float4*)(outf + ci) = ox;
        } else {
            if (2ULL*(ci + 4ULL) <= out_floats) {
                float2* o2 = (float2*)outf + ci;
                o2[0] = make_float2(ox.x, oy.x);
                o2[1] = make_float2(ox.y, oy.y);
                o2[2] = make_float2(ox.z, oy.z);
                o2[3] = make_float2(ox.w, oy.w);
            }
        }
    }
}

// ---------------------------------------------------------------------------
extern "C" void kernel_launch(void* const* d_in, const int* in_sizes, int n_in,
                              void* d_out, int out_size, void* d_ws, size_t ws_size,
                              hipStream_t stream)
{
    const int expect[12] = { cBN*cD, cD*cD, cD, 1, cD*cD, cD,
                             cD*cD, cD, 1, cD*cD, cD, cB*9 };
    bool ok = (n_in == 12);
    if (ok) for (int i = 0; i < 12; ++i) ok = ok && (in_sizes[i] == expect[i]);
    if (!ok) {
        sentinel_kernel<<<1, 1, 0, stream>>>((float*)d_out, out_size, 1.0e6f);
        return;
    }
    const size_t pBytes = (size_t)cB * 6 * cN * sizeof(float);       // 768 KB
    const size_t dBytes = (size_t)cBN * sizeof(float2);              // 256 KB
    const size_t wBytes = (size_t)4 * 65536 * sizeof(_Float16);      // 512 KB
    if (d_ws == nullptr || ws_size < pBytes + dBytes + wBytes) {
        sentinel_kernel<<<1, 1, 0, stream>>>((float*)d_out, out_size, 2.0e6f);
        return;
    }
    int mode;
    if (out_size == cBN * cD)          mode = 0;
    else if (out_size == 2 * cBN * cD) mode = 1;
    else {
        sentinel_kernel<<<1, 1, 0, stream>>>((float*)d_out, out_size, 3.0e6f);
        return;
    }

    const float* x     = (const float*)d_in[0];
    const float* ev_w1 = (const float*)d_in[1];
    const float* ev_b1 = (const float*)d_in[2];
    const float* ev_g  = (const float*)d_in[3];
    const float* ev_w2 = (const float*)d_in[4];
    const float* ev_b2 = (const float*)d_in[5];
    const float* hp_w1 = (const float*)d_in[6];
    const float* hp_b1 = (const float*)d_in[7];
    const float* hp_g  = (const float*)d_in[8];
    const float* hp_w2 = (const float*)d_in[9];
    const float* hp_b2 = (const float*)d_in[10];
    const float* cheb  = (const float*)d_in[11];

    float*     P    = (float*)d_ws;
    float2*    DIAG = (float2*)((char*)d_ws + pBytes);
    _Float16*  W16  = (_Float16*)((char*)d_ws + pBytes + dBytes);

    wcvt_kernel<<<dim3(256), 256, 0, stream>>>(ev_w1, ev_w2, hp_w1, hp_w2, W16);
    siren_mfma<<<dim3(cBN/64, 2), 512, 0, stream>>>(x, W16, ev_b1, ev_g, ev_b2,
                                                    hp_b1, hp_g, hp_b2, cheb, P, DIAG);
    dhhp_stencil<<<dim3(cN/32, cB), 256, 0, stream>>>(x, P, DIAG, (float*)d_out,
                                                      (unsigned long long)out_size,
                                                      mode);
}